// Round 8
// baseline (4442.187 us; speedup 1.0000x reference)
//
#include <hip/hip_runtime.h>
#include <math.h>

// ---------------- problem constants ----------------
#define BATCH   2
#define CIN     1024
#define COUT    1024
#define HH      50
#define WW      84
#define HWX     4200          // 50*84
#define NA      15
#define NSC     63000         // HWX*NA
#define TOPN    2000
#define POSTN   300
#define CAP     8192          // candidate capacity for top-k sort
#define CLS_OFF   0           // floats into d_out
#define BBOX_OFF  252000      // 2*30*4200
#define ROIS_OFF  756000      // + 2*60*4200
#define PROBS_OFF 759000      // + 600*5

__constant__ double ANCH[NA][4] = {
  {-15.0,  -4.0,  30.0, 19.0},
  {-38.0, -16.0,  53.0, 31.0},
  {-84.0, -40.0,  99.0, 55.0},
  {-176.0,-88.0, 191.0,103.0},
  {-360.0,-184.0,375.0,199.0},
  {-8.0,  -8.0,  23.0, 23.0},
  {-24.0, -24.0, 39.0, 39.0},
  {-56.0, -56.0, 71.0, 71.0},
  {-120.0,-120.0,135.0,135.0},
  {-248.0,-248.0,263.0,263.0},
  {-3.0, -14.0, 18.0, 29.0},
  {-14.0, -36.0, 29.0, 51.0},
  {-36.0, -80.0, 51.0, 95.0},
  {-80.0,-168.0, 95.0,183.0},
  {-168.0,-344.0,183.0,359.0}
};

#define BBOX_CLIP 4.1351665567423560     // log(1000/16) in double

typedef double dx4 __attribute__((ext_vector_type(4)));

// ================= K1: 3x3 conv + bias + relu, f64 MFMA =================
// NUMERICS (R2): score path must be fp64. R6 passed via layout-proof probe
// epilogue; 3.73 ms, MfmaUtil 60.5%, conflicts 3.39e8.
// R7 BUG: weight pointer co-stride was 576 float4s; actual is 2304
// (9216 floats/co). Fixed here; structure otherwise identical to R7:
//  * 2 M-tiles/wave: block 16 rows x 8 cols x 64 co (grid 88 x 16);
//    halves W restaging + W reads per mfma. f64-pipe floor 2.11 ms.
//  * W9 ds_read_b128 layout [row=tap*16+ci][stride 72]:
//      chunk 4*(co&15), sub ((co>>4 + (ci>>2))&3) — write-rotation makes
//      the four wq groups' bank sets disjoint (2-way, free); reads uniform
//      8 words/bank (72 = 8 mod 32). Readers un-rotate via bf[(nt+g)&3].
//  * XH stride 10 (no pad) -> LDS 52,992 B total -> 3 blocks/CU.
__launch_bounds__(256, 3)
__global__ void conv3x3_k(const float* __restrict__ xin,
                          const float* __restrict__ wcv,
                          const float* __restrict__ bias,
                          float* __restrict__ hout) {
  __shared__ __align__(16) float XH[16*180];   // [ci][row18][col10]  11.25 KB
  __shared__ __align__(16) float W9[144*72];   // [tap*16+ci][72]     40.5 KB
  const int tid  = threadIdx.x;
  const int lane = tid & 63;
  const int w    = tid >> 6;           // wave id
  const int sid  = blockIdx.x;         // 0..87 = b(2) x ry(4) x cx(11)
  const int b    = sid / 44;
  const int s    = sid % 44;
  const int ry   = s / 11, cx = s % 11;
  const int y0   = ry * 16, x0 = cx * 8;
  const int n0   = blockIdx.y * 64;

  const int q    = lane >> 4;          // k-slice index (ci within group of 4)
  const int m16  = lane & 15;          // A position label / B cout label
  const int laneA = q*180 + (2*w + (m16 >> 3))*10 + (m16 & 7); // + mt*80 + g*720 + dy*10 + dx
  const int laneB = q*72 + 4*m16;                              // + (tp*16+g*4)*72
  const bool skip0 = (y0 + 2*w) >= HH;           // tile0 rows {2w,2w+1}
  const bool skip1 = (y0 + 8 + 2*w) >= HH;       // tile1 rows {2w+8,2w+9}

  // ---- D-layout probe (data independent, verified R6) ----
  int pidx[4], nidx[4];
  {
    dx4 pr = {0.,0.,0.,0.}, pc = {0.,0.,0.,0.};
    pr = __builtin_amdgcn_mfma_f64_16x16x4f64((double)m16, 1.0, pr, 0, 0, 0);
    pc = __builtin_amdgcn_mfma_f64_16x16x4f64(1.0, (double)m16, pc, 0, 0, 0);
    #pragma unroll
    for (int i = 0; i < 4; ++i) {
      pidx[i] = ((int)pr[i]) >> 2;     // value = 4 * label
      nidx[i] = ((int)pc[i]) >> 2;
    }
  }

  // weight staging: 4 consecutive lanes read consecutive float4 runs of one co
  const int wco = tid >> 2;            // 0..63
  const int wq  = tid & 3;
  const int wp15 = wco & 15;
  const int wv   = wco >> 4;

  dx4 acc[2][4];
  #pragma unroll
  for (int mt = 0; mt < 2; ++mt)
    #pragma unroll
    for (int nt = 0; nt < 4; ++nt) acc[mt][nt] = (dx4){0.,0.,0.,0.};

  for (int st = 0; st < 64; ++st) {
    // ---- stage x halo (zero-padded): 16 ci x 18 rows x 10 cols ----
    for (int e = tid; e < 2880; e += 256) {
      int ci = e / 180; int r = e - ci*180;
      int yy = r / 10;  int xx = r - yy*10;
      int gy = y0 + yy - 1, gx = x0 + xx - 1;
      float v = 0.f;
      if ((unsigned)gy < (unsigned)HH && (unsigned)gx < (unsigned)WW)
        v = xin[((size_t)(b*CIN + st*16 + ci)*HH + gy)*WW + gx];
      XH[e] = v;
    }
    // ---- stage weights (rotated layout; writes exact 2-way = free) ----
    {
      // co stride = 9216 floats = 2304 float4s (R7 bug: was 576)
      const float4* wp = (const float4*)wcv + (size_t)(n0 + wco)*2304 + (size_t)st*36;
      #pragma unroll
      for (int i = 0; i < 9; ++i) {
        float4 w4 = wp[wq*9 + i];
        float wf[4] = {w4.x, w4.y, w4.z, w4.w};
        #pragma unroll
        for (int c = 0; c < 4; ++c) {
          // k = 36*wq + 4*i + c ; (4i+c) compile-time:
          const int ct = 4*i + c;
          int ci  = 4*wq + (ct/9);     // ct/9, ct%9 fold at compile time
          int tap = ct % 9;
          int row = tap*16 + ci;
          W9[row*72 + 4*wp15 + ((wv + wq) & 3)] = wf[c];
        }
      }
    }
    __syncthreads();

    {
      const float* XA = XH + laneA;
      const float* WB = W9 + laneB;
      #pragma unroll
      for (int g = 0; g < 4; ++g) {          // ci groups of 4
        #pragma unroll
        for (int dy = 0; dy < 3; ++dy) {
          #pragma unroll
          for (int dx = 0; dx < 3; ++dx) {
            const int tp = dy*3 + dx;
            // B fragment: one b128, un-rotate by compile-time (nt+g)&3
            float4 bb = *(const float4*)(WB + (tp*16 + g*4)*72);
            float bf[4] = {bb.x, bb.y, bb.z, bb.w};
            double b0 = (double)bf[(0 + g) & 3];
            double b1 = (double)bf[(1 + g) & 3];
            double b2 = (double)bf[(2 + g) & 3];
            double b3 = (double)bf[(3 + g) & 3];
            // A values for both M-tiles (adjacent reads -> ds_read2 fusable)
            double a0 = (double)XA[g*720 + dy*10 + dx];
            double a1 = (double)XA[g*720 + dy*10 + dx + 80];
            if (!skip0) {
              acc[0][0] = __builtin_amdgcn_mfma_f64_16x16x4f64(a0, b0, acc[0][0], 0, 0, 0);
              acc[0][1] = __builtin_amdgcn_mfma_f64_16x16x4f64(a0, b1, acc[0][1], 0, 0, 0);
              acc[0][2] = __builtin_amdgcn_mfma_f64_16x16x4f64(a0, b2, acc[0][2], 0, 0, 0);
              acc[0][3] = __builtin_amdgcn_mfma_f64_16x16x4f64(a0, b3, acc[0][3], 0, 0, 0);
            }
            if (!skip1) {
              acc[1][0] = __builtin_amdgcn_mfma_f64_16x16x4f64(a1, b0, acc[1][0], 0, 0, 0);
              acc[1][1] = __builtin_amdgcn_mfma_f64_16x16x4f64(a1, b1, acc[1][1], 0, 0, 0);
              acc[1][2] = __builtin_amdgcn_mfma_f64_16x16x4f64(a1, b2, acc[1][2], 0, 0, 0);
              acc[1][3] = __builtin_amdgcn_mfma_f64_16x16x4f64(a1, b3, acc[1][3], 0, 0, 0);
            }
          }
        }
      }
    }
    __syncthreads();
  }

  // ---- layout-proof epilogue: scatter via probed labels ----
  #pragma unroll
  for (int mt = 0; mt < 2; ++mt) {
    if (mt == 0 ? skip0 : skip1) continue;
    #pragma unroll
    for (int i = 0; i < 4; ++i) {
      const int yg = y0 + 2*w + 8*mt + (pidx[i] >> 3);
      const int xg = x0 + (pidx[i] & 7);
      if (xg < WW) {
        #pragma unroll
        for (int nt = 0; nt < 4; ++nt) {
          int co = n0 + nt*16 + nidx[i];
          double bv = (double)bias[co];
          hout[((size_t)(b*COUT + co)*HH + yg)*WW + xg] =
              (float)fmax(acc[mt][nt][i] + bv, 0.0);
        }
      }
    }
  }
}

// ================= K2a: transpose head weights to [c][96] =================
__global__ void wt_k(const float* __restrict__ cls_w, const float* __restrict__ bbox_w,
                     float* __restrict__ wT) {
  int t = blockIdx.x*256 + threadIdx.x;
  if (t >= 96*1024) return;
  int c = t / 96, o = t - (t/96)*96;
  float v = 0.f;
  if (o < 30)      v = cls_w[(size_t)o*1024 + c];
  else if (o < 90) v = bbox_w[(size_t)(o-30)*1024 + c];
  wT[t] = v;
}

// ================= K2: fused 1x1 heads (cls 30 + bbox 60), fp64 acc =================
__launch_bounds__(256)
__global__ void heads_k(const float* __restrict__ h, const float* __restrict__ wT,
                        const float* __restrict__ cls_b, const float* __restrict__ bbox_b,
                        float* __restrict__ out_cls, float* __restrict__ out_bbox) {
  __shared__ float Hs[32*64];   // [ci][mi]
  __shared__ float Ws[32*96];   // [ci][o]
  const int tid = threadIdx.x;
  const int b   = blockIdx.y;
  const int m0  = blockIdx.x * 64;
  const int tp  = tid & 15;     // 4 positions each
  const int to  = tid >> 4;     // 6 outputs each (16*6=96)

  double acc[4][6];
  #pragma unroll
  for (int i = 0; i < 4; ++i)
    #pragma unroll
    for (int j = 0; j < 6; ++j) acc[i][j] = 0.0;

  for (int c0 = 0; c0 < CIN; c0 += 32) {
    for (int e = tid; e < 2048; e += 256) {
      int ci = e >> 6, mi = e & 63; int m = m0 + mi;
      Hs[e] = (m < HWX) ? h[((size_t)b*COUT + c0 + ci)*HWX + m] : 0.f;
    }
    for (int e = tid; e < 3072; e += 256) {
      int ci = e / 96, o = e - ci*96;
      Ws[e] = wT[(size_t)(c0 + ci)*96 + o];
    }
    __syncthreads();
    #pragma unroll 8
    for (int ci = 0; ci < 32; ++ci) {
      double a[4], wv[6];
      #pragma unroll
      for (int i = 0; i < 4; ++i) a[i] = (double)Hs[ci*64 + tp*4 + i];
      #pragma unroll
      for (int j = 0; j < 6; ++j) wv[j] = (double)Ws[ci*96 + to*6 + j];
      #pragma unroll
      for (int i = 0; i < 4; ++i)
        #pragma unroll
        for (int j = 0; j < 6; ++j) acc[i][j] += a[i]*wv[j];
    }
    __syncthreads();
  }

  const int mb = m0 + tp*4;
  if (mb < HWX) {                         // all-or-none (HWX%4==0)
    #pragma unroll
    for (int j = 0; j < 6; ++j) {
      int o = to*6 + j;
      if (o < 30) {
        double bv = (double)cls_b[o];
        float4 v;
        v.x=(float)(acc[0][j]+bv); v.y=(float)(acc[1][j]+bv);
        v.z=(float)(acc[2][j]+bv); v.w=(float)(acc[3][j]+bv);
        *(float4*)&out_cls[((size_t)(b*30 + o))*HWX + mb] = v;
      } else if (o < 90) {
        int ob = o - 30;
        double bv = (double)bbox_b[ob];
        float4 v;
        v.x=(float)(acc[0][j]+bv); v.y=(float)(acc[1][j]+bv);
        v.z=(float)(acc[2][j]+bv); v.w=(float)(acc[3][j]+bv);
        *(float4*)&out_bbox[((size_t)(b*60 + ob))*HWX + mb] = v;
      }
    }
  }
}

// ================= K2b: scores = sigmoid(l1-l0), fp64 interior =================
__global__ void score_k(const float* __restrict__ out_cls, float* __restrict__ scores) {
  int t = blockIdx.x*256 + threadIdx.x;
  if (t >= BATCH*NSC) return;
  int b = t / NSC; int r = t - b*NSC;
  int m = r / NA;  int a = r - m*NA;
  float l0 = out_cls[((size_t)(b*30 + a))*HWX + m];
  float l1 = out_cls[((size_t)(b*30 + a + NA))*HWX + m];
  double p = 1.0 / (1.0 + exp((double)l0 - (double)l1));
  scores[t] = (float)p;
}

// ================= K3: per-image top-2000 (radix select + bitonic), stable ties =================
__launch_bounds__(1024)
__global__ void topk_k(const float* __restrict__ scores,
                       unsigned* __restrict__ top_idx, float* __restrict__ top_score) {
  __shared__ unsigned hist[256];
  __shared__ unsigned sh_b1, sh_need, sh_cut, sh_cnt;
  __shared__ unsigned long long key[CAP];
  const int b = blockIdx.x;
  const int tid = threadIdx.x;
  const float* sc = scores + (size_t)b*NSC;

  if (tid < 256) hist[tid] = 0;
  __syncthreads();
  for (int i = tid; i < NSC; i += 1024) {
    unsigned k = __float_as_uint(sc[i]);
    atomicAdd(&hist[k >> 24], 1u);
  }
  __syncthreads();
  if (tid == 0) {
    unsigned cum = 0; int bin = 255;
    for (; bin >= 0; --bin) { cum += hist[bin]; if (cum >= TOPN) break; }
    sh_b1 = (unsigned)bin;
    sh_need = TOPN - (cum - hist[bin]);
  }
  __syncthreads();
  const unsigned b1 = sh_b1, need = sh_need;
  if (tid < 256) hist[tid] = 0;
  __syncthreads();
  for (int i = tid; i < NSC; i += 1024) {
    unsigned k = __float_as_uint(sc[i]);
    if ((k >> 24) == b1) atomicAdd(&hist[(k >> 16) & 255u], 1u);
  }
  __syncthreads();
  if (tid == 0) {
    unsigned cum = 0; int bin = 255;
    for (; bin >= 0; --bin) { cum += hist[bin]; if (cum >= need) break; }
    sh_cut = (b1 << 8) | (unsigned)bin;
    sh_cnt = 0;
  }
  __syncthreads();
  const unsigned cut = sh_cut;
  for (int i = tid; i < CAP; i += 1024) key[i] = 0ull;
  __syncthreads();
  for (int i = tid; i < NSC; i += 1024) {
    unsigned k = __float_as_uint(sc[i]);
    if ((k >> 16) >= cut) {
      unsigned p = atomicAdd(&sh_cnt, 1u);
      if (p < CAP)
        key[p] = ((unsigned long long)k << 32) | (unsigned long long)(0xFFFFFFFFu - (unsigned)i);
    }
  }
  __syncthreads();
  // bitonic sort, DESCENDING by (score_bits, -idx)
  for (int k2 = 2; k2 <= CAP; k2 <<= 1) {
    for (int j = k2 >> 1; j > 0; j >>= 1) {
      for (int i = tid; i < CAP; i += 1024) {
        int p = i ^ j;
        if (p > i) {
          unsigned long long a = key[i], c = key[p];
          bool up = ((i & k2) == 0);
          if (up ? (a < c) : (a > c)) { key[i] = c; key[p] = a; }
        }
      }
      __syncthreads();
    }
  }
  for (int i = tid; i < TOPN; i += 1024) {
    unsigned long long kk = key[i];
    top_idx[(size_t)b*TOPN + i]   = 0xFFFFFFFFu - (unsigned)(kk & 0xFFFFFFFFull);
    top_score[(size_t)b*TOPN + i] = __uint_as_float((unsigned)(kk >> 32));
  }
}

// ================= K4: decode + clip top boxes (fp64) =================
__global__ void decode_k(const unsigned* __restrict__ top_idx,
                         const float* __restrict__ out_bbox,
                         const float* __restrict__ im_info,
                         double* __restrict__ boxesd) {
  int t = blockIdx.x*256 + threadIdx.x;
  if (t >= BATCH*TOPN) return;
  int b = t / TOPN;
  unsigned idx = top_idx[t];
  int a = idx % NA; int m = idx / NA;
  int yy = m / WW;  int xx = m - yy*WW;
  double sx = (double)xx * 16.0, sy = (double)yy * 16.0;
  double A0 = ANCH[a][0] + sx, A1 = ANCH[a][1] + sy;
  double A2 = ANCH[a][2] + sx, A3 = ANCH[a][3] + sy;
  double w_ = A2 - A0 + 1.0, h_ = A3 - A1 + 1.0;
  double cx = A0 + 0.5*w_,  cy = A1 + 0.5*h_;
  const float* bp = out_bbox + (size_t)b*60*HWX;
  double dx = (double)bp[(a*4+0)*HWX + m];
  double dy = (double)bp[(a*4+1)*HWX + m];
  double dw = fmin((double)bp[(a*4+2)*HWX + m], BBOX_CLIP);
  double dh = fmin((double)bp[(a*4+3)*HWX + m], BBOX_CLIP);
  double pcx = dx*w_ + cx, pcy = dy*h_ + cy;
  double pw = exp(dw)*w_,  ph = exp(dh)*h_;
  double x1 = pcx - 0.5*pw, y1 = pcy - 0.5*ph;
  double x2 = pcx + 0.5*pw - 1.0, y2 = pcy + 0.5*ph - 1.0;
  double hmax = (double)im_info[b*3+0] - 1.0;
  double wmax = (double)im_info[b*3+1] - 1.0;
  x1 = fmin(fmax(x1, 0.0), wmax); x2 = fmin(fmax(x2, 0.0), wmax);
  y1 = fmin(fmax(y1, 0.0), hmax); y2 = fmin(fmax(y2, 0.0), hmax);
  boxesd[(size_t)t*4+0] = x1; boxesd[(size_t)t*4+1] = y1;
  boxesd[(size_t)t*4+2] = x2; boxesd[(size_t)t*4+3] = y2;
}

// ================= K5: IoU suppression bitmask (fp64) =================
__launch_bounds__(256)
__global__ void iou_k(const double* __restrict__ boxesd,
                      unsigned long long* __restrict__ mask) {
  __shared__ double BX[TOPN*4];    // 64 KB
  const int b  = blockIdx.y;
  const int i0 = blockIdx.x * 8;
  const double* src = boxesd + (size_t)b*TOPN*4;
  for (int e = threadIdx.x; e < TOPN*4; e += 256) BX[e] = src[e];
  __syncthreads();
  const int il = threadIdx.x >> 5;
  const int w  = threadIdx.x & 31;
  const int i  = i0 + il;
  double x1 = BX[i*4+0], y1 = BX[i*4+1], x2 = BX[i*4+2], y2 = BX[i*4+3];
  double ai = (x2 - x1 + 1.0)*(y2 - y1 + 1.0);
  unsigned long long bits = 0ull;
  for (int jj = 0; jj < 64; ++jj) {
    int j = w*64 + jj;
    if (j >= TOPN) break;
    double bx1 = BX[j*4+0], by1 = BX[j*4+1], bx2 = BX[j*4+2], by2 = BX[j*4+3];
    double xx1 = fmax(x1, bx1), yy1 = fmax(y1, by1);
    double xx2 = fmin(x2, bx2), yy2 = fmin(y2, by2);
    double iw = fmax(xx2 - xx1 + 1.0, 0.0);
    double ih = fmax(yy2 - yy1 + 1.0, 0.0);
    double inter = iw * ih;
    double aj = (bx2 - bx1 + 1.0)*(by2 - by1 + 1.0);
    double iou = inter / (ai + aj - inter);
    if (iou > 0.7) bits |= (1ull << jj);
  }
  mask[((size_t)b*TOPN + i)*32 + w] = bits;
}

// ================= K6: serial NMS scan + prefix + emit rois/probs =================
__launch_bounds__(256)
__global__ void nms_out_k(const unsigned long long* __restrict__ mask,
                          const double* __restrict__ boxesd,
                          const float* __restrict__ top_score,
                          float* __restrict__ rois, float* __restrict__ probs) {
  __shared__ unsigned long long MS[256*32];  // 64 KB chunk of mask rows
  __shared__ unsigned keepf[2048];
  __shared__ unsigned psum[256];
  const int b = blockIdx.x;
  const int tid = threadIdx.x;
  for (int i = tid; i < 2048; i += 256) keepf[i] = 0;

  unsigned long long acc = 0ull;             // lanes 0..31 of wave 0
  for (int ch = 0; ch < 8; ++ch) {
    const int base = ch * 256;
    __syncthreads();
    for (int e = tid; e < 256*32; e += 256) {
      int row = base + (e >> 5);
      MS[e] = (row < TOPN) ? mask[((size_t)b*TOPN + row)*32 + (e & 31)] : 0ull;
    }
    __syncthreads();
    if (tid < 64) {
      const int lane = tid;
      for (int r = 0; r < 256; ++r) {
        int i = base + r;
        if (i >= TOPN) break;
        unsigned long long wv = __shfl(acc, i >> 6);
        if (!((wv >> (i & 63)) & 1ull)) {
          if (lane == 0) keepf[i] = 1;
          if (lane < 32) acc |= MS[r*32 + lane];
        }
      }
    }
  }
  __syncthreads();

  // prefix sum over keepf[0..1999]; thread t owns indices t*8..t*8+7
  const int base0 = tid * 8;
  unsigned lsum = 0;
  #pragma unroll
  for (int q = 0; q < 8; ++q) { int i = base0 + q; if (i < TOPN) lsum += keepf[i]; }
  psum[tid] = lsum;
  __syncthreads();
  for (int off = 1; off < 256; off <<= 1) {
    unsigned v = (tid >= off) ? psum[tid - off] : 0u;
    __syncthreads();
    psum[tid] += v;
    __syncthreads();
  }
  unsigned rank = (tid == 0) ? 0u : psum[tid - 1];

  // zero-init all rows (coords + probs), batch id column
  for (int j = tid; j < POSTN; j += 256) {
    float* rr = rois + ((size_t)b*POSTN + j)*5;
    rr[0] = (float)b; rr[1] = 0.f; rr[2] = 0.f; rr[3] = 0.f; rr[4] = 0.f;
    probs[(size_t)b*POSTN + j] = 0.f;
  }
  __syncthreads();

  for (int q = 0; q < 8; ++q) {
    int i = base0 + q;
    if (i < TOPN && keepf[i]) {
      if (rank < POSTN) {
        const double* bx = boxesd + ((size_t)b*TOPN + i)*4;
        float* rr = rois + ((size_t)b*POSTN + rank)*5;
        rr[1] = (float)bx[0]; rr[2] = (float)bx[1];
        rr[3] = (float)bx[2]; rr[4] = (float)bx[3];
        probs[(size_t)b*POSTN + rank] = top_score[(size_t)b*TOPN + i];
      }
      rank++;
    }
  }
}

// ================= launch =================
extern "C" void kernel_launch(void* const* d_in, const int* in_sizes, int n_in,
                              void* d_out, int out_size, void* d_ws, size_t ws_size,
                              hipStream_t stream) {
  const float* x      = (const float*)d_in[0];
  const float* conv_w = (const float*)d_in[1];
  const float* conv_b = (const float*)d_in[2];
  const float* cls_w  = (const float*)d_in[3];
  const float* cls_b  = (const float*)d_in[4];
  const float* bbox_w = (const float*)d_in[5];
  const float* bbox_b = (const float*)d_in[6];
  const float* im_info= (const float*)d_in[7];

  float* out  = (float*)d_out;
  float* out_cls  = out + CLS_OFF;
  float* out_bbox = out + BBOX_OFF;
  float* rois     = out + ROIS_OFF;
  float* probs    = out + PROBS_OFF;

  // workspace layout (float-slot offsets; boxesd/mask 8B-aligned by construction)
  float* wsf = (float*)d_ws;
  float*    h       = wsf;                              // 8,601,600 f
  float*    wT      = wsf + 8601600;                    //   98,304 f
  float*    scores  = wsf + 8699904;                    //  126,000 f
  unsigned* top_idx = (unsigned*)(wsf + 8825904);       //    4,000 u32
  float*    top_sc  = wsf + 8829904;                    //    4,000 f
  double*   boxesd  = (double*)(wsf + 8833904);         //   16,000 f64 (32,000 slots)
  unsigned long long* mask = (unsigned long long*)(wsf + 8865904); // 128,000 u64

  wt_k<<<dim3((96*1024 + 255)/256), dim3(256), 0, stream>>>(cls_w, bbox_w, wT);
  conv3x3_k<<<dim3(88, 16), dim3(256), 0, stream>>>(x, conv_w, conv_b, h);
  heads_k<<<dim3(66, 2), dim3(256), 0, stream>>>(h, wT, cls_b, bbox_b, out_cls, out_bbox);
  score_k<<<dim3((BATCH*NSC + 255)/256), dim3(256), 0, stream>>>(out_cls, scores);
  topk_k<<<dim3(2), dim3(1024), 0, stream>>>(scores, top_idx, top_sc);
  decode_k<<<dim3((BATCH*TOPN + 255)/256), dim3(256), 0, stream>>>(top_idx, out_bbox, im_info, boxesd);
  iou_k<<<dim3(TOPN/8, 2), dim3(256), 0, stream>>>(boxesd, mask);
  nms_out_k<<<dim3(2), dim3(256), 0, stream>>>(mask, boxesd, top_sc, rois, probs);
}

// Round 9
// 4067.007 us; speedup vs baseline: 1.0922x; 1.0922x over previous
//
#include <hip/hip_runtime.h>
#include <math.h>

// ---------------- problem constants ----------------
#define BATCH   2
#define CIN     1024
#define COUT    1024
#define HH      50
#define WW      84
#define HWX     4200          // 50*84
#define NA      15
#define NSC     63000         // HWX*NA
#define TOPN    2000
#define POSTN   300
#define CAP     8192          // candidate capacity for top-k sort
#define CLS_OFF   0           // floats into d_out
#define BBOX_OFF  252000      // 2*30*4200
#define ROIS_OFF  756000      // + 2*60*4200
#define PROBS_OFF 759000      // + 600*5

__constant__ double ANCH[NA][4] = {
  {-15.0,  -4.0,  30.0, 19.0},
  {-38.0, -16.0,  53.0, 31.0},
  {-84.0, -40.0,  99.0, 55.0},
  {-176.0,-88.0, 191.0,103.0},
  {-360.0,-184.0,375.0,199.0},
  {-8.0,  -8.0,  23.0, 23.0},
  {-24.0, -24.0, 39.0, 39.0},
  {-56.0, -56.0, 71.0, 71.0},
  {-120.0,-120.0,135.0,135.0},
  {-248.0,-248.0,263.0,263.0},
  {-3.0, -14.0, 18.0, 29.0},
  {-14.0, -36.0, 29.0, 51.0},
  {-36.0, -80.0, 51.0, 95.0},
  {-80.0,-168.0, 95.0,183.0},
  {-168.0,-344.0,183.0,359.0}
};

#define BBOX_CLIP 4.1351665567423560     // log(1000/16) in double

typedef double dx4 __attribute__((ext_vector_type(4)));

// ================= K1: 3x3 conv + bias + relu, f64 MFMA =================
// NUMERICS (R2): score path must be fp64. Probe epilogue (R6) handles the
// unknown f64 MFMA D-layout. R8: 3.74 ms, MfmaUtil 60%, conflicts fixed but
// NOT the bottleneck — the 40% pipe idle is the staging->barrier drain
// (global-load latency exposed between barriers). R9: software pipeline —
// prefetch stage st+1 into REGISTERS while mfma computes stage st; the only
// exposed serial work is regs->LDS (~50cyc) + 2 barriers.
//   loop: regs->LDS; sync; issue loads(st+1); mfma(st); sync
// X addresses precomputed per-thread once (xoff[12]); W is 9 float4/thread.
// LDS single-buffered: XH 2880 f + W9 144*72 f = 52,992 B -> 3 blocks/CU.
__launch_bounds__(256, 3)
__global__ void conv3x3_k(const float* __restrict__ xin,
                          const float* __restrict__ wcv,
                          const float* __restrict__ bias,
                          float* __restrict__ hout) {
  __shared__ __align__(16) float XH[2880];     // [ci16][row18][col10]
  __shared__ __align__(16) float W9[144*72];   // [tap*16+ci][72]
  const int tid  = threadIdx.x;
  const int lane = tid & 63;
  const int w    = tid >> 6;           // wave id
  const int sid  = blockIdx.x;         // 0..87 = b(2) x ry(4) x cx(11)
  const int b    = sid / 44;
  const int s    = sid % 44;
  const int ry   = s / 11, cx = s % 11;
  const int y0   = ry * 16, x0 = cx * 8;
  const int n0   = blockIdx.y * 64;

  const int q    = lane >> 4;          // k-slice index
  const int m16  = lane & 15;          // A position label / B cout label
  const int laneA = q*180 + (2*w + (m16 >> 3))*10 + (m16 & 7);
  const int laneB = q*72 + 4*m16;
  const bool skip0 = (y0 + 2*w) >= HH;
  const bool skip1 = (y0 + 8 + 2*w) >= HH;

  // ---- D-layout probe (data independent, verified R6) ----
  int pidx[4], nidx[4];
  {
    dx4 pr = {0.,0.,0.,0.}, pc = {0.,0.,0.,0.};
    pr = __builtin_amdgcn_mfma_f64_16x16x4f64((double)m16, 1.0, pr, 0, 0, 0);
    pc = __builtin_amdgcn_mfma_f64_16x16x4f64(1.0, (double)m16, pc, 0, 0, 0);
    #pragma unroll
    for (int i = 0; i < 4; ++i) {
      pidx[i] = ((int)pr[i]) >> 2;     // value = 4 * label
      nidx[i] = ((int)pc[i]) >> 2;
    }
  }

  // weight staging assignment
  const int wco = tid >> 2;            // 0..63
  const int wq  = tid & 3;
  const int wp15 = wco & 15;
  const int wv   = wco >> 4;

  // ---- precompute per-thread X prefetch slots (offset or -1) ----
  const float* xbase = xin + (size_t)b*CIN*HH*WW;
  int xoff[12];
  #pragma unroll
  for (int i = 0; i < 12; ++i) {
    int e = tid + i*256;
    int v = -1;
    if (e < 2880) {
      int ci = e / 180; int r = e - ci*180;
      int yy = r / 10;  int xx = r - yy*10;
      int gy = y0 + yy - 1, gx = x0 + xx - 1;
      if ((unsigned)gy < (unsigned)HH && (unsigned)gx < (unsigned)WW)
        v = (ci*HH + gy)*WW + gx;
    }
    xoff[i] = v;
  }
  const float4* wbase = (const float4*)wcv + (size_t)(n0 + wco)*2304 + wq*9;

  float  xv[12];
  float4 wv4[9];

  // ---- prefetch stage 0 ----
  #pragma unroll
  for (int i = 0; i < 12; ++i) xv[i] = (xoff[i] >= 0) ? xbase[xoff[i]] : 0.f;
  #pragma unroll
  for (int i = 0; i < 9; ++i)  wv4[i] = wbase[i];

  dx4 acc[2][4];
  #pragma unroll
  for (int mt = 0; mt < 2; ++mt)
    #pragma unroll
    for (int nt = 0; nt < 4; ++nt) acc[mt][nt] = (dx4){0.,0.,0.,0.};

  for (int st = 0; st < 64; ++st) {
    // ---- regs -> LDS (waits on the prefetch's vmcnt only here) ----
    #pragma unroll
    for (int i = 0; i < 12; ++i) {
      int e = tid + i*256;
      if (e < 2880) XH[e] = xv[i];
    }
    #pragma unroll
    for (int i = 0; i < 9; ++i) {
      float wf[4] = {wv4[i].x, wv4[i].y, wv4[i].z, wv4[i].w};
      #pragma unroll
      for (int c = 0; c < 4; ++c) {
        const int ct = 4*i + c;            // compile-time
        int ci  = 4*wq + (ct/9);
        int tap = ct % 9;
        W9[(tap*16 + ci)*72 + 4*wp15 + ((wv + wq) & 3)] = wf[c];
      }
    }
    __syncthreads();

    // ---- issue global prefetch for st+1; latency hides under mfma ----
    if (st < 63) {
      const float* xs = xbase + (size_t)(st+1)*(16*HH*WW);
      #pragma unroll
      for (int i = 0; i < 12; ++i) xv[i] = (xoff[i] >= 0) ? xs[xoff[i]] : 0.f;
      const float4* ws = wbase + (size_t)(st+1)*36;
      #pragma unroll
      for (int i = 0; i < 9; ++i) wv4[i] = ws[i];
    }

    // ---- compute ----
    {
      const float* XA = XH + laneA;
      const float* WB = W9 + laneB;
      #pragma unroll
      for (int g = 0; g < 4; ++g) {          // ci groups of 4
        #pragma unroll
        for (int dy = 0; dy < 3; ++dy) {
          #pragma unroll
          for (int dx = 0; dx < 3; ++dx) {
            const int tp = dy*3 + dx;
            float4 bb = *(const float4*)(WB + (tp*16 + g*4)*72);
            float bf[4] = {bb.x, bb.y, bb.z, bb.w};
            double b0 = (double)bf[(0 + g) & 3];
            double b1 = (double)bf[(1 + g) & 3];
            double b2 = (double)bf[(2 + g) & 3];
            double b3 = (double)bf[(3 + g) & 3];
            double a0 = (double)XA[g*720 + dy*10 + dx];
            double a1 = (double)XA[g*720 + dy*10 + dx + 80];
            if (!skip0) {
              acc[0][0] = __builtin_amdgcn_mfma_f64_16x16x4f64(a0, b0, acc[0][0], 0, 0, 0);
              acc[0][1] = __builtin_amdgcn_mfma_f64_16x16x4f64(a0, b1, acc[0][1], 0, 0, 0);
              acc[0][2] = __builtin_amdgcn_mfma_f64_16x16x4f64(a0, b2, acc[0][2], 0, 0, 0);
              acc[0][3] = __builtin_amdgcn_mfma_f64_16x16x4f64(a0, b3, acc[0][3], 0, 0, 0);
            }
            if (!skip1) {
              acc[1][0] = __builtin_amdgcn_mfma_f64_16x16x4f64(a1, b0, acc[1][0], 0, 0, 0);
              acc[1][1] = __builtin_amdgcn_mfma_f64_16x16x4f64(a1, b1, acc[1][1], 0, 0, 0);
              acc[1][2] = __builtin_amdgcn_mfma_f64_16x16x4f64(a1, b2, acc[1][2], 0, 0, 0);
              acc[1][3] = __builtin_amdgcn_mfma_f64_16x16x4f64(a1, b3, acc[1][3], 0, 0, 0);
            }
          }
        }
      }
    }
    __syncthreads();
  }

  // ---- layout-proof epilogue: scatter via probed labels ----
  #pragma unroll
  for (int mt = 0; mt < 2; ++mt) {
    if (mt == 0 ? skip0 : skip1) continue;
    #pragma unroll
    for (int i = 0; i < 4; ++i) {
      const int yg = y0 + 2*w + 8*mt + (pidx[i] >> 3);
      const int xg = x0 + (pidx[i] & 7);
      if (xg < WW) {
        #pragma unroll
        for (int nt = 0; nt < 4; ++nt) {
          int co = n0 + nt*16 + nidx[i];
          double bv = (double)bias[co];
          hout[((size_t)(b*COUT + co)*HH + yg)*WW + xg] =
              (float)fmax(acc[mt][nt][i] + bv, 0.0);
        }
      }
    }
  }
}

// ================= K2a: transpose head weights to [c][96] =================
__global__ void wt_k(const float* __restrict__ cls_w, const float* __restrict__ bbox_w,
                     float* __restrict__ wT) {
  int t = blockIdx.x*256 + threadIdx.x;
  if (t >= 96*1024) return;
  int c = t / 96, o = t - (t/96)*96;
  float v = 0.f;
  if (o < 30)      v = cls_w[(size_t)o*1024 + c];
  else if (o < 90) v = bbox_w[(size_t)(o-30)*1024 + c];
  wT[t] = v;
}

// ================= K2: fused 1x1 heads (cls 30 + bbox 60), fp64 acc =================
__launch_bounds__(256)
__global__ void heads_k(const float* __restrict__ h, const float* __restrict__ wT,
                        const float* __restrict__ cls_b, const float* __restrict__ bbox_b,
                        float* __restrict__ out_cls, float* __restrict__ out_bbox) {
  __shared__ float Hs[32*64];   // [ci][mi]
  __shared__ float Ws[32*96];   // [ci][o]
  const int tid = threadIdx.x;
  const int b   = blockIdx.y;
  const int m0  = blockIdx.x * 64;
  const int tp  = tid & 15;     // 4 positions each
  const int to  = tid >> 4;     // 6 outputs each (16*6=96)

  double acc[4][6];
  #pragma unroll
  for (int i = 0; i < 4; ++i)
    #pragma unroll
    for (int j = 0; j < 6; ++j) acc[i][j] = 0.0;

  for (int c0 = 0; c0 < CIN; c0 += 32) {
    for (int e = tid; e < 2048; e += 256) {
      int ci = e >> 6, mi = e & 63; int m = m0 + mi;
      Hs[e] = (m < HWX) ? h[((size_t)b*COUT + c0 + ci)*HWX + m] : 0.f;
    }
    for (int e = tid; e < 3072; e += 256) {
      int ci = e / 96, o = e - ci*96;
      Ws[e] = wT[(size_t)(c0 + ci)*96 + o];
    }
    __syncthreads();
    #pragma unroll 8
    for (int ci = 0; ci < 32; ++ci) {
      double a[4], wv[6];
      #pragma unroll
      for (int i = 0; i < 4; ++i) a[i] = (double)Hs[ci*64 + tp*4 + i];
      #pragma unroll
      for (int j = 0; j < 6; ++j) wv[j] = (double)Ws[ci*96 + to*6 + j];
      #pragma unroll
      for (int i = 0; i < 4; ++i)
        #pragma unroll
        for (int j = 0; j < 6; ++j) acc[i][j] += a[i]*wv[j];
    }
    __syncthreads();
  }

  const int mb = m0 + tp*4;
  if (mb < HWX) {                         // all-or-none (HWX%4==0)
    #pragma unroll
    for (int j = 0; j < 6; ++j) {
      int o = to*6 + j;
      if (o < 30) {
        double bv = (double)cls_b[o];
        float4 v;
        v.x=(float)(acc[0][j]+bv); v.y=(float)(acc[1][j]+bv);
        v.z=(float)(acc[2][j]+bv); v.w=(float)(acc[3][j]+bv);
        *(float4*)&out_cls[((size_t)(b*30 + o))*HWX + mb] = v;
      } else if (o < 90) {
        int ob = o - 30;
        double bv = (double)bbox_b[ob];
        float4 v;
        v.x=(float)(acc[0][j]+bv); v.y=(float)(acc[1][j]+bv);
        v.z=(float)(acc[2][j]+bv); v.w=(float)(acc[3][j]+bv);
        *(float4*)&out_bbox[((size_t)(b*60 + ob))*HWX + mb] = v;
      }
    }
  }
}

// ================= K2b: scores = sigmoid(l1-l0), fp64 interior =================
__global__ void score_k(const float* __restrict__ out_cls, float* __restrict__ scores) {
  int t = blockIdx.x*256 + threadIdx.x;
  if (t >= BATCH*NSC) return;
  int b = t / NSC; int r = t - b*NSC;
  int m = r / NA;  int a = r - m*NA;
  float l0 = out_cls[((size_t)(b*30 + a))*HWX + m];
  float l1 = out_cls[((size_t)(b*30 + a + NA))*HWX + m];
  double p = 1.0 / (1.0 + exp((double)l0 - (double)l1));
  scores[t] = (float)p;
}

// ================= K3: per-image top-2000 (radix select + bitonic), stable ties =================
__launch_bounds__(1024)
__global__ void topk_k(const float* __restrict__ scores,
                       unsigned* __restrict__ top_idx, float* __restrict__ top_score) {
  __shared__ unsigned hist[256];
  __shared__ unsigned sh_b1, sh_need, sh_cut, sh_cnt;
  __shared__ unsigned long long key[CAP];
  const int b = blockIdx.x;
  const int tid = threadIdx.x;
  const float* sc = scores + (size_t)b*NSC;

  if (tid < 256) hist[tid] = 0;
  __syncthreads();
  for (int i = tid; i < NSC; i += 1024) {
    unsigned k = __float_as_uint(sc[i]);
    atomicAdd(&hist[k >> 24], 1u);
  }
  __syncthreads();
  if (tid == 0) {
    unsigned cum = 0; int bin = 255;
    for (; bin >= 0; --bin) { cum += hist[bin]; if (cum >= TOPN) break; }
    sh_b1 = (unsigned)bin;
    sh_need = TOPN - (cum - hist[bin]);
  }
  __syncthreads();
  const unsigned b1 = sh_b1, need = sh_need;
  if (tid < 256) hist[tid] = 0;
  __syncthreads();
  for (int i = tid; i < NSC; i += 1024) {
    unsigned k = __float_as_uint(sc[i]);
    if ((k >> 24) == b1) atomicAdd(&hist[(k >> 16) & 255u], 1u);
  }
  __syncthreads();
  if (tid == 0) {
    unsigned cum = 0; int bin = 255;
    for (; bin >= 0; --bin) { cum += hist[bin]; if (cum >= need) break; }
    sh_cut = (b1 << 8) | (unsigned)bin;
    sh_cnt = 0;
  }
  __syncthreads();
  const unsigned cut = sh_cut;
  for (int i = tid; i < CAP; i += 1024) key[i] = 0ull;
  __syncthreads();
  for (int i = tid; i < NSC; i += 1024) {
    unsigned k = __float_as_uint(sc[i]);
    if ((k >> 16) >= cut) {
      unsigned p = atomicAdd(&sh_cnt, 1u);
      if (p < CAP)
        key[p] = ((unsigned long long)k << 32) | (unsigned long long)(0xFFFFFFFFu - (unsigned)i);
    }
  }
  __syncthreads();
  // bitonic sort, DESCENDING by (score_bits, -idx)
  for (int k2 = 2; k2 <= CAP; k2 <<= 1) {
    for (int j = k2 >> 1; j > 0; j >>= 1) {
      for (int i = tid; i < CAP; i += 1024) {
        int p = i ^ j;
        if (p > i) {
          unsigned long long a = key[i], c = key[p];
          bool up = ((i & k2) == 0);
          if (up ? (a < c) : (a > c)) { key[i] = c; key[p] = a; }
        }
      }
      __syncthreads();
    }
  }
  for (int i = tid; i < TOPN; i += 1024) {
    unsigned long long kk = key[i];
    top_idx[(size_t)b*TOPN + i]   = 0xFFFFFFFFu - (unsigned)(kk & 0xFFFFFFFFull);
    top_score[(size_t)b*TOPN + i] = __uint_as_float((unsigned)(kk >> 32));
  }
}

// ================= K4: decode + clip top boxes (fp64) =================
__global__ void decode_k(const unsigned* __restrict__ top_idx,
                         const float* __restrict__ out_bbox,
                         const float* __restrict__ im_info,
                         double* __restrict__ boxesd) {
  int t = blockIdx.x*256 + threadIdx.x;
  if (t >= BATCH*TOPN) return;
  int b = t / TOPN;
  unsigned idx = top_idx[t];
  int a = idx % NA; int m = idx / NA;
  int yy = m / WW;  int xx = m - yy*WW;
  double sx = (double)xx * 16.0, sy = (double)yy * 16.0;
  double A0 = ANCH[a][0] + sx, A1 = ANCH[a][1] + sy;
  double A2 = ANCH[a][2] + sx, A3 = ANCH[a][3] + sy;
  double w_ = A2 - A0 + 1.0, h_ = A3 - A1 + 1.0;
  double cx = A0 + 0.5*w_,  cy = A1 + 0.5*h_;
  const float* bp = out_bbox + (size_t)b*60*HWX;
  double dx = (double)bp[(a*4+0)*HWX + m];
  double dy = (double)bp[(a*4+1)*HWX + m];
  double dw = fmin((double)bp[(a*4+2)*HWX + m], BBOX_CLIP);
  double dh = fmin((double)bp[(a*4+3)*HWX + m], BBOX_CLIP);
  double pcx = dx*w_ + cx, pcy = dy*h_ + cy;
  double pw = exp(dw)*w_,  ph = exp(dh)*h_;
  double x1 = pcx - 0.5*pw, y1 = pcy - 0.5*ph;
  double x2 = pcx + 0.5*pw - 1.0, y2 = pcy + 0.5*ph - 1.0;
  double hmax = (double)im_info[b*3+0] - 1.0;
  double wmax = (double)im_info[b*3+1] - 1.0;
  x1 = fmin(fmax(x1, 0.0), wmax); x2 = fmin(fmax(x2, 0.0), wmax);
  y1 = fmin(fmax(y1, 0.0), hmax); y2 = fmin(fmax(y2, 0.0), hmax);
  boxesd[(size_t)t*4+0] = x1; boxesd[(size_t)t*4+1] = y1;
  boxesd[(size_t)t*4+2] = x2; boxesd[(size_t)t*4+3] = y2;
}

// ================= K5: IoU suppression bitmask (fp64) =================
__launch_bounds__(256)
__global__ void iou_k(const double* __restrict__ boxesd,
                      unsigned long long* __restrict__ mask) {
  __shared__ double BX[TOPN*4];    // 64 KB
  const int b  = blockIdx.y;
  const int i0 = blockIdx.x * 8;
  const double* src = boxesd + (size_t)b*TOPN*4;
  for (int e = threadIdx.x; e < TOPN*4; e += 256) BX[e] = src[e];
  __syncthreads();
  const int il = threadIdx.x >> 5;
  const int w  = threadIdx.x & 31;
  const int i  = i0 + il;
  double x1 = BX[i*4+0], y1 = BX[i*4+1], x2 = BX[i*4+2], y2 = BX[i*4+3];
  double ai = (x2 - x1 + 1.0)*(y2 - y1 + 1.0);
  unsigned long long bits = 0ull;
  for (int jj = 0; jj < 64; ++jj) {
    int j = w*64 + jj;
    if (j >= TOPN) break;
    double bx1 = BX[j*4+0], by1 = BX[j*4+1], bx2 = BX[j*4+2], by2 = BX[j*4+3];
    double xx1 = fmax(x1, bx1), yy1 = fmax(y1, by1);
    double xx2 = fmin(x2, bx2), yy2 = fmin(y2, by2);
    double iw = fmax(xx2 - xx1 + 1.0, 0.0);
    double ih = fmax(yy2 - yy1 + 1.0, 0.0);
    double inter = iw * ih;
    double aj = (bx2 - bx1 + 1.0)*(by2 - by1 + 1.0);
    double iou = inter / (ai + aj - inter);
    if (iou > 0.7) bits |= (1ull << jj);
  }
  mask[((size_t)b*TOPN + i)*32 + w] = bits;
}

// ================= K6: serial NMS scan + prefix + emit rois/probs =================
__launch_bounds__(256)
__global__ void nms_out_k(const unsigned long long* __restrict__ mask,
                          const double* __restrict__ boxesd,
                          const float* __restrict__ top_score,
                          float* __restrict__ rois, float* __restrict__ probs) {
  __shared__ unsigned long long MS[256*32];  // 64 KB chunk of mask rows
  __shared__ unsigned keepf[2048];
  __shared__ unsigned psum[256];
  const int b = blockIdx.x;
  const int tid = threadIdx.x;
  for (int i = tid; i < 2048; i += 256) keepf[i] = 0;

  unsigned long long acc = 0ull;             // lanes 0..31 of wave 0
  for (int ch = 0; ch < 8; ++ch) {
    const int base = ch * 256;
    __syncthreads();
    for (int e = tid; e < 256*32; e += 256) {
      int row = base + (e >> 5);
      MS[e] = (row < TOPN) ? mask[((size_t)b*TOPN + row)*32 + (e & 31)] : 0ull;
    }
    __syncthreads();
    if (tid < 64) {
      const int lane = tid;
      for (int r = 0; r < 256; ++r) {
        int i = base + r;
        if (i >= TOPN) break;
        unsigned long long wv = __shfl(acc, i >> 6);
        if (!((wv >> (i & 63)) & 1ull)) {
          if (lane == 0) keepf[i] = 1;
          if (lane < 32) acc |= MS[r*32 + lane];
        }
      }
    }
  }
  __syncthreads();

  // prefix sum over keepf[0..1999]; thread t owns indices t*8..t*8+7
  const int base0 = tid * 8;
  unsigned lsum = 0;
  #pragma unroll
  for (int q = 0; q < 8; ++q) { int i = base0 + q; if (i < TOPN) lsum += keepf[i]; }
  psum[tid] = lsum;
  __syncthreads();
  for (int off = 1; off < 256; off <<= 1) {
    unsigned v = (tid >= off) ? psum[tid - off] : 0u;
    __syncthreads();
    psum[tid] += v;
    __syncthreads();
  }
  unsigned rank = (tid == 0) ? 0u : psum[tid - 1];

  // zero-init all rows (coords + probs), batch id column
  for (int j = tid; j < POSTN; j += 256) {
    float* rr = rois + ((size_t)b*POSTN + j)*5;
    rr[0] = (float)b; rr[1] = 0.f; rr[2] = 0.f; rr[3] = 0.f; rr[4] = 0.f;
    probs[(size_t)b*POSTN + j] = 0.f;
  }
  __syncthreads();

  for (int q = 0; q < 8; ++q) {
    int i = base0 + q;
    if (i < TOPN && keepf[i]) {
      if (rank < POSTN) {
        const double* bx = boxesd + ((size_t)b*TOPN + i)*4;
        float* rr = rois + ((size_t)b*POSTN + rank)*5;
        rr[1] = (float)bx[0]; rr[2] = (float)bx[1];
        rr[3] = (float)bx[2]; rr[4] = (float)bx[3];
        probs[(size_t)b*POSTN + rank] = top_score[(size_t)b*TOPN + i];
      }
      rank++;
    }
  }
}

// ================= launch =================
extern "C" void kernel_launch(void* const* d_in, const int* in_sizes, int n_in,
                              void* d_out, int out_size, void* d_ws, size_t ws_size,
                              hipStream_t stream) {
  const float* x      = (const float*)d_in[0];
  const float* conv_w = (const float*)d_in[1];
  const float* conv_b = (const float*)d_in[2];
  const float* cls_w  = (const float*)d_in[3];
  const float* cls_b  = (const float*)d_in[4];
  const float* bbox_w = (const float*)d_in[5];
  const float* bbox_b = (const float*)d_in[6];
  const float* im_info= (const float*)d_in[7];

  float* out  = (float*)d_out;
  float* out_cls  = out + CLS_OFF;
  float* out_bbox = out + BBOX_OFF;
  float* rois     = out + ROIS_OFF;
  float* probs    = out + PROBS_OFF;

  // workspace layout (float-slot offsets; boxesd/mask 8B-aligned by construction)
  float* wsf = (float*)d_ws;
  float*    h       = wsf;                              // 8,601,600 f
  float*    wT      = wsf + 8601600;                    //   98,304 f
  float*    scores  = wsf + 8699904;                    //  126,000 f
  unsigned* top_idx = (unsigned*)(wsf + 8825904);       //    4,000 u32
  float*    top_sc  = wsf + 8829904;                    //    4,000 f
  double*   boxesd  = (double*)(wsf + 8833904);         //   16,000 f64 (32,000 slots)
  unsigned long long* mask = (unsigned long long*)(wsf + 8865904); // 128,000 u64

  wt_k<<<dim3((96*1024 + 255)/256), dim3(256), 0, stream>>>(cls_w, bbox_w, wT);
  conv3x3_k<<<dim3(88, 16), dim3(256), 0, stream>>>(x, conv_w, conv_b, h);
  heads_k<<<dim3(66, 2), dim3(256), 0, stream>>>(h, wT, cls_b, bbox_b, out_cls, out_bbox);
  score_k<<<dim3((BATCH*NSC + 255)/256), dim3(256), 0, stream>>>(out_cls, scores);
  topk_k<<<dim3(2), dim3(1024), 0, stream>>>(scores, top_idx, top_sc);
  decode_k<<<dim3((BATCH*TOPN + 255)/256), dim3(256), 0, stream>>>(top_idx, out_bbox, im_info, boxesd);
  iou_k<<<dim3(TOPN/8, 2), dim3(256), 0, stream>>>(boxesd, mask);
  nms_out_k<<<dim3(2), dim3(256), 0, stream>>>(mask, boxesd, top_sc, rois, probs);
}